// Round 1
// baseline (3965.943 us; speedup 1.0000x reference)
//
#include <hip/hip_runtime.h>
#include <float.h>
#include <math.h>

// Problem constants
#define B_ 16
#define N_ 4096
#define S_ 1024
#define K_ 32
#define CIN0 67              // 3 + 64
#define NBS (B_ * S_)        // 16384
#define NEWXYZ_FLOATS (B_ * S_ * 3)  // 49152
#define AST 68               // LDS activation row stride (67/64 + pad -> 4k+c banks, conflict-free)

// ---------------- helpers ----------------

__device__ __forceinline__ float sqdist3(float x, float y, float z,
                                         float cx, float cy, float cz) {
#pragma clang fp contract(off)
  float dx = x - cx, dy = y - cy, dz = z - cz;
  float s = dx * dx;
  s = s + dy * dy;
  s = s + dz * dz;
  return s;
}

// ---------------- FPS: one block per batch ----------------
// Sequential scan, must match numpy bit-exactly: contract(off) distances,
// first-index argmax tie-breaking.
__global__ __launch_bounds__(1024) void fps_kernel(
    const float* __restrict__ xyz, float* __restrict__ newxyz) {
  const int b = blockIdx.x;
  const int t = threadIdx.x;
  __shared__ float sx[N_ * 3];
  __shared__ float wval[16];
  __shared__ int widx[16];
  __shared__ int sfar;
  const float* xb = xyz + (size_t)b * N_ * 3;
  for (int i = t; i < N_ * 3; i += 1024) sx[i] = xb[i];
  float dist[4];
#pragma unroll
  for (int j = 0; j < 4; ++j) dist[j] = 1e10f;
  __syncthreads();
  int far = 0;
  for (int s = 0; s < S_; ++s) {
    const float cx = sx[far * 3 + 0];
    const float cy = sx[far * 3 + 1];
    const float cz = sx[far * 3 + 2];
    if (t == 0) {
      float* o = newxyz + ((size_t)b * S_ + s) * 3;
      o[0] = cx; o[1] = cy; o[2] = cz;
    }
    float best = -1.0f;
    int bi = 0;
#pragma unroll
    for (int j = 0; j < 4; ++j) {
      const int p = t + j * 1024;  // ascending index -> strict '>' keeps first
      const float d = sqdist3(sx[p * 3 + 0], sx[p * 3 + 1], sx[p * 3 + 2], cx, cy, cz);
      const float nd = fminf(dist[j], d);
      dist[j] = nd;
      if (nd > best) { best = nd; bi = p; }
    }
    // wave argmax (tie -> smaller index)
#pragma unroll
    for (int off = 32; off >= 1; off >>= 1) {
      const float ov = __shfl_xor(best, off);
      const int oi = __shfl_xor(bi, off);
      if (ov > best || (ov == best && oi < bi)) { best = ov; bi = oi; }
    }
    if ((t & 63) == 0) { wval[t >> 6] = best; widx[t >> 6] = bi; }
    __syncthreads();
    if (t == 0) {
      float bv = wval[0]; int bj = widx[0];
      for (int w = 1; w < 16; ++w) {
        if (wval[w] > bv || (wval[w] == bv && widx[w] < bj)) { bv = wval[w]; bj = widx[w]; }
      }
      sfar = bj;
    }
    __syncthreads();
    far = sfar;
  }
}

// ---------------- KNN: one block per (b,s) query ----------------
// Same distance formula as reference; 32x argmin-with-removal (tie -> smaller idx).
// Only the SET of K indices matters downstream (max-pool/BN are permutation-invariant).
__global__ __launch_bounds__(256) void knn_kernel(
    const float* __restrict__ xyz, const float* __restrict__ newxyz,
    int* __restrict__ knn_idx) {
  const int bs = blockIdx.x;
  const int b = bs >> 10;
  const int t = threadIdx.x;
  __shared__ float sd[N_];
  __shared__ float wval[4];
  __shared__ int widx[4];
  const float* xb = xyz + (size_t)b * N_ * 3;
  const float cx = newxyz[(size_t)bs * 3 + 0];
  const float cy = newxyz[(size_t)bs * 3 + 1];
  const float cz = newxyz[(size_t)bs * 3 + 2];
  float c2;
  {
#pragma clang fp contract(off)
    float s = cx * cx;
    s = s + cy * cy;
    s = s + cz * cz;
    c2 = s;
  }
  for (int i = t; i < N_; i += 256) {
#pragma clang fp contract(off)
    const float x = xb[i * 3 + 0];
    const float y = xb[i * 3 + 1];
    const float z = xb[i * 3 + 2];
    float dot = cx * x; dot = dot + cy * y; dot = dot + cz * z;
    float x2 = x * x;   x2 = x2 + y * y;   x2 = x2 + z * z;
    float d = c2 - 2.0f * dot;
    d = d + x2;
    sd[i] = d;
  }
  __syncthreads();
  int* krow = knn_idx + (size_t)bs * K_;
  for (int j = 0; j < K_; ++j) {
    float best = FLT_MAX;
    int bi = N_;
#pragma unroll
    for (int m = 0; m < 16; ++m) {
      const int i = t + m * 256;  // ascending -> strict '<' keeps first
      const float v = sd[i];
      if (v < best) { best = v; bi = i; }
    }
#pragma unroll
    for (int off = 32; off >= 1; off >>= 1) {
      const float ov = __shfl_xor(best, off);
      const int oi = __shfl_xor(bi, off);
      if (ov < best || (ov == best && oi < bi)) { best = ov; bi = oi; }
    }
    if ((t & 63) == 0) { wval[t >> 6] = best; widx[t >> 6] = bi; }
    __syncthreads();
    if (t == 0) {
      float bv = wval[0]; int bj = widx[0];
      for (int w = 1; w < 4; ++w) {
        if (wval[w] < bv || (wval[w] == bv && widx[w] < bj)) { bv = wval[w]; bj = widx[w]; }
      }
      krow[j] = bj;
      sd[bj] = FLT_MAX;
    }
    __syncthreads();
  }
}

// ---------------- MLP pass building blocks ----------------

__device__ __forceinline__ void loadw(float* __restrict__ wbuf,
                                      const float* __restrict__ w, int n, int t) {
  for (int i = t; i < n; i += 256) wbuf[i] = w[i];
}

// w2 [64][128] row-major -> wbuf [64][64] = columns ofs..ofs+63
__device__ __forceinline__ void loadw_half(float* __restrict__ wbuf,
                                           const float* __restrict__ w2, int ofs, int t) {
  for (int i = t; i < 64 * 64; i += 256) {
    const int c = i >> 6, j = i & 63;
    wbuf[i] = w2[c * 128 + ofs + j];
  }
}

// Gather + center + concat -> actA [32][AST], 67 valid channels
__device__ __forceinline__ void build_x0(float* __restrict__ act,
    const float* __restrict__ xyz, const float* __restrict__ points,
    const int* __restrict__ knn_idx, const float* __restrict__ newxyz,
    int bs, int t) {
  const int b = bs >> 10;
  const int* krow = knn_idx + (size_t)bs * K_;
  const float cx = newxyz[(size_t)bs * 3 + 0];
  const float cy = newxyz[(size_t)bs * 3 + 1];
  const float cz = newxyz[(size_t)bs * 3 + 2];
  for (int i = t; i < K_ * CIN0; i += 256) {
    const int k = i / CIN0;
    const int c = i - k * CIN0;
    const int p = krow[k];
    float v;
    if (c < 3) {
      v = xyz[((size_t)b * N_ + p) * 3 + c] - (c == 0 ? cx : (c == 1 ? cy : cz));
    } else {
      v = points[((size_t)b * N_ + p) * 64 + (c - 3)];
    }
    act[k * AST + c] = v;
  }
}

// 32x64 output tile: thread t -> point k=t>>3, channels (t&7)*8 .. +7 (contiguous)
template <int CIN>
__device__ __forceinline__ void matmul64(const float* __restrict__ act,
    const float* __restrict__ wbuf, const float* __restrict__ bias,
    float* __restrict__ out, int t) {
  const int k = t >> 3;
  const int g = t & 7;
  float acc[8];
#pragma unroll
  for (int j = 0; j < 8; ++j) acc[j] = bias[g * 8 + j];
  for (int c = 0; c < CIN; ++c) {
    const float xv = act[k * AST + c];
#pragma unroll
    for (int j = 0; j < 8; ++j) acc[j] += xv * wbuf[c * 64 + g * 8 + j];
  }
#pragma unroll
  for (int j = 0; j < 8; ++j) out[k * AST + g * 8 + j] = acc[j];
}

__device__ __forceinline__ void norm_relu64(float* __restrict__ act,
    const float* __restrict__ scale, const float* __restrict__ shift, int t) {
  for (int i = t; i < K_ * 64; i += 256) {
    const int k = i >> 6, c = i & 63;
    const float v = act[k * AST + c] * scale[c] + shift[c];
    act[k * AST + c] = fmaxf(v, 0.0f);
  }
}

// deterministic per-block channel partials (no atomics)
__device__ __forceinline__ void stats64(const float* __restrict__ out,
    float* __restrict__ psum, float* __restrict__ psq, int bs, int ofs, int t) {
  if (t < 64) {
    float s = 0.f, q = 0.f;
    for (int k = 0; k < K_; ++k) {
      const float v = out[k * AST + t];
      s += v; q += v * v;
    }
    psum[(size_t)bs * 128 + ofs + t] = s;
    psq[(size_t)bs * 128 + ofs + t] = q;
  }
}

__device__ __forceinline__ void minmax64(const float* __restrict__ out,
    float* __restrict__ maxraw, float* __restrict__ minbuf, int bs, int ofs, int t) {
  if (t >= 64 && t < 128) {
    const int ch = t - 64;
    float mx = -FLT_MAX, mn = FLT_MAX;
    for (int k = 0; k < K_; ++k) {
      const float v = out[k * AST + ch];
      mx = fmaxf(mx, v); mn = fminf(mn, v);
    }
    maxraw[(size_t)bs * 128 + ofs + ch] = mx;
    minbuf[(size_t)bs * 128 + ofs + ch] = mn;
  }
}

// ---------------- Pass A: layer0 stats ----------------
__global__ __launch_bounds__(256) void passA_kernel(
    const float* __restrict__ xyz, const float* __restrict__ points,
    const float* __restrict__ newxyz, const int* __restrict__ knn_idx,
    const float* __restrict__ w0, const float* __restrict__ b0,
    float* __restrict__ psum, float* __restrict__ psq) {
  __shared__ float actA[K_ * AST];
  __shared__ float outB[K_ * AST];
  __shared__ float wbuf[CIN0 * 64];
  const int bs = blockIdx.x, t = threadIdx.x;
  build_x0(actA, xyz, points, knn_idx, newxyz, bs, t);
  loadw(wbuf, w0, CIN0 * 64, t);
  __syncthreads();
  matmul64<CIN0>(actA, wbuf, b0, outB, t);
  __syncthreads();
  stats64(outB, psum, psq, bs, 0, t);
}

// ---------------- Pass B: recompute layer0, layer1 stats ----------------
__global__ __launch_bounds__(256) void passB_kernel(
    const float* __restrict__ xyz, const float* __restrict__ points,
    const float* __restrict__ newxyz, const int* __restrict__ knn_idx,
    const float* __restrict__ w0, const float* __restrict__ b0,
    const float* __restrict__ w1, const float* __restrict__ b1,
    const float* __restrict__ scales, const float* __restrict__ shifts,
    float* __restrict__ psum, float* __restrict__ psq) {
  __shared__ float actA[K_ * AST];
  __shared__ float outB[K_ * AST];
  __shared__ float wbuf[CIN0 * 64];
  const int bs = blockIdx.x, t = threadIdx.x;
  build_x0(actA, xyz, points, knn_idx, newxyz, bs, t);
  loadw(wbuf, w0, CIN0 * 64, t);
  __syncthreads();
  matmul64<CIN0>(actA, wbuf, b0, outB, t);
  __syncthreads();
  norm_relu64(outB, scales, shifts, t);
  loadw(wbuf, w1, 64 * 64, t);
  __syncthreads();
  matmul64<64>(outB, wbuf, b1, actA, t);
  __syncthreads();
  stats64(actA, psum, psq, bs, 0, t);
}

// ---------------- Pass C: recompute through layer2; stats + per-(b,s,ch) min/max ----------------
__global__ __launch_bounds__(256) void passC_kernel(
    const float* __restrict__ xyz, const float* __restrict__ points,
    const float* __restrict__ newxyz, const int* __restrict__ knn_idx,
    const float* __restrict__ w0, const float* __restrict__ b0,
    const float* __restrict__ w1, const float* __restrict__ b1,
    const float* __restrict__ w2, const float* __restrict__ b2,
    const float* __restrict__ scales, const float* __restrict__ shifts,
    float* __restrict__ psum, float* __restrict__ psq,
    float* __restrict__ maxraw, float* __restrict__ minbuf) {
  __shared__ float actA[K_ * AST];
  __shared__ float outB[K_ * AST];
  __shared__ float wbuf[CIN0 * 64];
  const int bs = blockIdx.x, t = threadIdx.x;
  build_x0(actA, xyz, points, knn_idx, newxyz, bs, t);
  loadw(wbuf, w0, CIN0 * 64, t);
  __syncthreads();
  matmul64<CIN0>(actA, wbuf, b0, outB, t);
  __syncthreads();
  norm_relu64(outB, scales, shifts, t);          // layer0 scale/shift
  loadw(wbuf, w1, 64 * 64, t);
  __syncthreads();
  matmul64<64>(outB, wbuf, b1, actA, t);          // out1 -> actA
  __syncthreads();
  norm_relu64(actA, scales + 128, shifts + 128, t);  // layer1 scale/shift
  loadw_half(wbuf, w2, 0, t);
  __syncthreads();
  matmul64<64>(actA, wbuf, b2, outB, t);          // layer2 cols 0..63
  __syncthreads();
  stats64(outB, psum, psq, bs, 0, t);
  minmax64(outB, maxraw, minbuf, bs, 0, t);
  loadw_half(wbuf, w2, 64, t);
  __syncthreads();
  matmul64<64>(actA, wbuf, b2 + 64, outB, t);     // layer2 cols 64..127
  __syncthreads();
  stats64(outB, psum, psq, bs, 64, t);
  minmax64(outB, maxraw, minbuf, bs, 64, t);
}

// ---------------- BN finalize: deterministic fixed-order reduction ----------------
__global__ __launch_bounds__(256) void finalize_kernel(
    const float* __restrict__ psum, const float* __restrict__ psq,
    const float* __restrict__ g, const float* __restrict__ be,
    float* __restrict__ scale, float* __restrict__ shift) {
  const int ch = blockIdx.x, t = threadIdx.x;
  __shared__ float ss[256];
  __shared__ float sq[256];
  float s = 0.f, q = 0.f;
  for (int p = t; p < NBS; p += 256) {
    s += psum[(size_t)p * 128 + ch];
    q += psq[(size_t)p * 128 + ch];
  }
  ss[t] = s; sq[t] = q;
  __syncthreads();
  for (int off = 128; off >= 1; off >>= 1) {
    if (t < off) { ss[t] += ss[t + off]; sq[t] += sq[t + off]; }
    __syncthreads();
  }
  if (t == 0) {
    const float invN = 1.0f / (float)(B_ * S_ * K_);
    const float mean = ss[0] * invN;
    const float var = sq[0] * invN - mean * mean;
    const float sc = g[ch] / sqrtf(var + 1e-5f);
    scale[ch] = sc;
    shift[ch] = be[ch] - mean * sc;
  }
}

// ---------------- Final: max_k relu(sc*x+sh) = relu(sc>=0 ? sc*max+sh : sc*min+sh) ----------------
__global__ __launch_bounds__(256) void final_kernel(
    const float* __restrict__ minbuf, const float* __restrict__ scale,
    const float* __restrict__ shift, float* __restrict__ out) {
  const int i = blockIdx.x * 256 + threadIdx.x;  // < B*S*128
  const int ch = i & 127;
  const float sc = scale[ch], sh = shift[ch];
  const float mx = out[NEWXYZ_FLOATS + i];  // raw max written by passC
  const float mn = minbuf[i];
  const float v = sc * (sc >= 0.f ? mx : mn) + sh;
  out[NEWXYZ_FLOATS + i] = fmaxf(v, 0.f);
}

// ---------------- host ----------------
extern "C" void kernel_launch(void* const* d_in, const int* in_sizes, int n_in,
                              void* d_out, int out_size, void* d_ws, size_t ws_size,
                              hipStream_t stream) {
  const float* xyz = (const float*)d_in[0];
  const float* points = (const float*)d_in[1];
  const float* w0 = (const float*)d_in[2];
  const float* b0 = (const float*)d_in[3];
  const float* g0 = (const float*)d_in[4];
  const float* be0 = (const float*)d_in[5];
  const float* w1 = (const float*)d_in[6];
  const float* b1 = (const float*)d_in[7];
  const float* g1 = (const float*)d_in[8];
  const float* be1 = (const float*)d_in[9];
  const float* w2 = (const float*)d_in[10];
  const float* b2 = (const float*)d_in[11];
  const float* g2 = (const float*)d_in[12];
  const float* be2 = (const float*)d_in[13];
  float* out = (float*)d_out;

  // Workspace layout (floats): ~27.3 MB total
  float* ws = (float*)d_ws;
  int* knn_idx = (int*)ws;                 // B*S*K = 524288 ints
  float* psum = ws + 524288;               // 16384*128
  float* psq = psum + (size_t)NBS * 128;   // 16384*128
  float* scales = psq + (size_t)NBS * 128; // 3*128
  float* shifts = scales + 384;            // 3*128
  float* minbuf = shifts + 384;            // B*S*128
  float* newxyz = out;                     // first 49152 floats of d_out
  float* maxraw = out + NEWXYZ_FLOATS;     // raw max staged in d_out's new_points region

  fps_kernel<<<B_, 1024, 0, stream>>>(xyz, newxyz);
  knn_kernel<<<NBS, 256, 0, stream>>>(xyz, newxyz, knn_idx);
  passA_kernel<<<NBS, 256, 0, stream>>>(xyz, points, newxyz, knn_idx, w0, b0, psum, psq);
  finalize_kernel<<<64, 256, 0, stream>>>(psum, psq, g0, be0, scales, shifts);
  passB_kernel<<<NBS, 256, 0, stream>>>(xyz, points, newxyz, knn_idx, w0, b0, w1, b1,
                                        scales, shifts, psum, psq);
  finalize_kernel<<<64, 256, 0, stream>>>(psum, psq, g1, be1, scales + 128, shifts + 128);
  passC_kernel<<<NBS, 256, 0, stream>>>(xyz, points, newxyz, knn_idx, w0, b0, w1, b1, w2, b2,
                                        scales, shifts, psum, psq, maxraw, minbuf);
  finalize_kernel<<<128, 256, 0, stream>>>(psum, psq, g2, be2, scales + 256, shifts + 256);
  final_kernel<<<(B_ * S_ * 128) / 256, 256, 0, stream>>>(minbuf, scales + 256, shifts + 256, out);
}

// Round 2
// 2523.925 us; speedup vs baseline: 1.5713x; 1.5713x over previous
//
#include <hip/hip_runtime.h>
#include <float.h>
#include <math.h>

// Problem constants
#define B_ 16
#define N_ 4096
#define S_ 1024
#define K_ 32
#define CIN0 67              // 3 + 64
#define NBS (B_ * S_)        // 16384
#define NEWXYZ_FLOATS (B_ * S_ * 3)  // 49152
#define AST 68               // LDS activation row stride

// ---------------- helpers ----------------

__device__ __forceinline__ float sqdist3(float x, float y, float z,
                                         float cx, float cy, float cz) {
#pragma clang fp contract(off)
  float dx = x - cx, dy = y - cy, dz = z - cz;
  float s = dx * dx;
  s = s + dy * dy;
  s = s + dz * dz;
  return s;
}

__device__ __forceinline__ float knn_dist(float c2, float cx, float cy, float cz,
                                          float x, float y, float z) {
#pragma clang fp contract(off)
  float dot = cx * x; dot = dot + cy * y; dot = dot + cz * z;
  float x2 = x * x;   x2 = x2 + y * y;   x2 = x2 + z * z;
  float d = c2 - 2.0f * dot;
  d = d + x2;
  return d;
}

// ---------------- FPS: one block (256 thr) per batch ----------------
// Points held in registers (16/thread). One barrier per step, double-buffered
// wave results, redundant all-thread resolve. Bit-exact vs numpy: contract(off)
// distances, first-index argmax tie-breaking.
__global__ __launch_bounds__(256) void fps_kernel(
    const float* __restrict__ xyz, float* __restrict__ newxyz) {
  const int b = blockIdx.x;
  const int t = threadIdx.x;
  __shared__ float sx[N_ * 3];
  __shared__ float rval[2][4];
  __shared__ int ridx[2][4];
  const float* xb = xyz + (size_t)b * N_ * 3;
  for (int i = t; i < N_ * 3; i += 256) sx[i] = xb[i];
  __syncthreads();
  // preload this thread's 16 consecutive points into registers
  float px[16], py[16], pz[16], dist[16];
#pragma unroll
  for (int j = 0; j < 16; ++j) {
    const int p = t * 16 + j;
    px[j] = sx[p * 3 + 0];
    py[j] = sx[p * 3 + 1];
    pz[j] = sx[p * 3 + 2];
    dist[j] = 1e10f;
  }
  int far = 0;
  for (int s = 0; s < S_; ++s) {
    const float cx = sx[far * 3 + 0];
    const float cy = sx[far * 3 + 1];
    const float cz = sx[far * 3 + 2];
    if (t == 0) {
      float* o = newxyz + ((size_t)b * S_ + s) * 3;
      o[0] = cx; o[1] = cy; o[2] = cz;
    }
    float best = -1.0f;
    int bi = 0;
#pragma unroll
    for (int j = 0; j < 16; ++j) {  // ascending global idx -> strict '>' keeps first
      const float dd = sqdist3(px[j], py[j], pz[j], cx, cy, cz);
      const float nd = fminf(dist[j], dd);
      dist[j] = nd;
      if (nd > best) { best = nd; bi = t * 16 + j; }
    }
    // wave argmax (tie -> smaller index)
#pragma unroll
    for (int off = 32; off >= 1; off >>= 1) {
      const float ov = __shfl_xor(best, off);
      const int oi = __shfl_xor(bi, off);
      if (ov > best || (ov == best && oi < bi)) { best = ov; bi = oi; }
    }
    const int par = s & 1;
    if ((t & 63) == 0) { rval[par][t >> 6] = best; ridx[par][t >> 6] = bi; }
    __syncthreads();
    // all threads resolve the 4 wave candidates redundantly
    float bv = rval[par][0];
    int bj = ridx[par][0];
#pragma unroll
    for (int w = 1; w < 4; ++w) {
      const float v = rval[par][w];
      const int iw = ridx[par][w];
      if (v > bv || (v == bv && iw < bj)) { bv = v; bj = iw; }
    }
    far = bj;
  }
}

// ---------------- KNN: one wave per query, 4 queries/block ----------------
// Distances register-resident (d[64]/lane, 8 groups of 8 with cached group mins).
// 32x argmin-with-removal; tie -> smaller global index (matches top_k set).
__global__ __launch_bounds__(256, 2) void knn_kernel(
    const float* __restrict__ xyz, const float* __restrict__ newxyz,
    int* __restrict__ knn_idx) {
  const int bs0 = blockIdx.x * 4;
  const int b = bs0 >> 10;
  const int t = threadIdx.x;
  const int wave = t >> 6;
  const int lane = t & 63;
  __shared__ float sxx[N_];
  __shared__ float sxy[N_];
  __shared__ float sxz[N_];
  const float* xb = xyz + (size_t)b * N_ * 3;
  for (int p = t; p < N_; p += 256) {
    sxx[p] = xb[p * 3 + 0];
    sxy[p] = xb[p * 3 + 1];
    sxz[p] = xb[p * 3 + 2];
  }
  __syncthreads();
  const int bs = bs0 + wave;
  const float cx = newxyz[(size_t)bs * 3 + 0];
  const float cy = newxyz[(size_t)bs * 3 + 1];
  const float cz = newxyz[(size_t)bs * 3 + 2];
  float c2;
  {
#pragma clang fp contract(off)
    float s = cx * cx;
    s = s + cy * cy;
    s = s + cz * cz;
    c2 = s;
  }
  // distances: point p = j*64 + lane (j=0..63), conflict-free LDS reads
  float d[64];
  float gval[8];
  int gidx[8];
#pragma unroll
  for (int g = 0; g < 8; ++g) {
    float gv = FLT_MAX;
    int gi = g * 8;
#pragma unroll
    for (int q = 0; q < 8; ++q) {
      const int j = g * 8 + q;
      const int p = j * 64 + lane;
      const float dd = knn_dist(c2, cx, cy, cz, sxx[p], sxy[p], sxz[p]);
      d[j] = dd;
      if (dd < gv) { gv = dd; gi = j; }  // ascending j, strict '<' keeps first
    }
    gval[g] = gv; gidx[g] = gi;
  }
  int* krow = knn_idx + (size_t)bs * K_;
  for (int it = 0; it < K_; ++it) {
    // lane candidate: min over 8 group mins (tie -> smaller local j)
    float best = gval[0];
    int bj = gidx[0];
#pragma unroll
    for (int g = 1; g < 8; ++g) {
      if (gval[g] < best || (gval[g] == best && gidx[g] < bj)) { best = gval[g]; bj = gidx[g]; }
    }
    int bidx = bj * 64 + lane;  // global point index
    // wave argmin (tie -> smaller global index)
#pragma unroll
    for (int off = 32; off >= 1; off >>= 1) {
      const float ov = __shfl_xor(best, off);
      const int oi = __shfl_xor(bidx, off);
      if (ov < best || (ov == best && oi < bidx)) { best = ov; bidx = oi; }
    }
    if (lane == 0) krow[it] = bidx;
    // winner lane removes the point and repairs its group min
    if (lane == (bidx & 63)) {
      const int jl = bidx >> 6;
      const int gg = jl >> 3;
      const int qq = jl & 7;
#pragma unroll
      for (int g = 0; g < 8; ++g) {
        if (g == gg) {
#pragma unroll
          for (int q = 0; q < 8; ++q) {
            d[g * 8 + q] = (q == qq) ? FLT_MAX : d[g * 8 + q];
          }
          float gv = FLT_MAX;
          int gi = g * 8;
#pragma unroll
          for (int q = 0; q < 8; ++q) {
            const int j = g * 8 + q;
            if (d[j] < gv) { gv = d[j]; gi = j; }
          }
          gval[g] = gv; gidx[g] = gi;
        }
      }
    }
  }
}

// ---------------- MLP pass building blocks (unchanged) ----------------

__device__ __forceinline__ void loadw(float* __restrict__ wbuf,
                                      const float* __restrict__ w, int n, int t) {
  for (int i = t; i < n; i += 256) wbuf[i] = w[i];
}

__device__ __forceinline__ void loadw_half(float* __restrict__ wbuf,
                                           const float* __restrict__ w2, int ofs, int t) {
  for (int i = t; i < 64 * 64; i += 256) {
    const int c = i >> 6, j = i & 63;
    wbuf[i] = w2[c * 128 + ofs + j];
  }
}

__device__ __forceinline__ void build_x0(float* __restrict__ act,
    const float* __restrict__ xyz, const float* __restrict__ points,
    const int* __restrict__ knn_idx, const float* __restrict__ newxyz,
    int bs, int t) {
  const int b = bs >> 10;
  const int* krow = knn_idx + (size_t)bs * K_;
  const float cx = newxyz[(size_t)bs * 3 + 0];
  const float cy = newxyz[(size_t)bs * 3 + 1];
  const float cz = newxyz[(size_t)bs * 3 + 2];
  for (int i = t; i < K_ * CIN0; i += 256) {
    const int k = i / CIN0;
    const int c = i - k * CIN0;
    const int p = krow[k];
    float v;
    if (c < 3) {
      v = xyz[((size_t)b * N_ + p) * 3 + c] - (c == 0 ? cx : (c == 1 ? cy : cz));
    } else {
      v = points[((size_t)b * N_ + p) * 64 + (c - 3)];
    }
    act[k * AST + c] = v;
  }
}

template <int CIN>
__device__ __forceinline__ void matmul64(const float* __restrict__ act,
    const float* __restrict__ wbuf, const float* __restrict__ bias,
    float* __restrict__ out, int t) {
  const int k = t >> 3;
  const int g = t & 7;
  float acc[8];
#pragma unroll
  for (int j = 0; j < 8; ++j) acc[j] = bias[g * 8 + j];
  for (int c = 0; c < CIN; ++c) {
    const float xv = act[k * AST + c];
#pragma unroll
    for (int j = 0; j < 8; ++j) acc[j] += xv * wbuf[c * 64 + g * 8 + j];
  }
#pragma unroll
  for (int j = 0; j < 8; ++j) out[k * AST + g * 8 + j] = acc[j];
}

__device__ __forceinline__ void norm_relu64(float* __restrict__ act,
    const float* __restrict__ scale, const float* __restrict__ shift, int t) {
  for (int i = t; i < K_ * 64; i += 256) {
    const int k = i >> 6, c = i & 63;
    const float v = act[k * AST + c] * scale[c] + shift[c];
    act[k * AST + c] = fmaxf(v, 0.0f);
  }
}

__device__ __forceinline__ void stats64(const float* __restrict__ out,
    float* __restrict__ psum, float* __restrict__ psq, int bs, int ofs, int t) {
  if (t < 64) {
    float s = 0.f, q = 0.f;
    for (int k = 0; k < K_; ++k) {
      const float v = out[k * AST + t];
      s += v; q += v * v;
    }
    psum[(size_t)bs * 128 + ofs + t] = s;
    psq[(size_t)bs * 128 + ofs + t] = q;
  }
}

__device__ __forceinline__ void minmax64(const float* __restrict__ out,
    float* __restrict__ maxraw, float* __restrict__ minbuf, int bs, int ofs, int t) {
  if (t >= 64 && t < 128) {
    const int ch = t - 64;
    float mx = -FLT_MAX, mn = FLT_MAX;
    for (int k = 0; k < K_; ++k) {
      const float v = out[k * AST + ch];
      mx = fmaxf(mx, v); mn = fminf(mn, v);
    }
    maxraw[(size_t)bs * 128 + ofs + ch] = mx;
    minbuf[(size_t)bs * 128 + ofs + ch] = mn;
  }
}

// ---------------- Pass A ----------------
__global__ __launch_bounds__(256) void passA_kernel(
    const float* __restrict__ xyz, const float* __restrict__ points,
    const float* __restrict__ newxyz, const int* __restrict__ knn_idx,
    const float* __restrict__ w0, const float* __restrict__ b0,
    float* __restrict__ psum, float* __restrict__ psq) {
  __shared__ float actA[K_ * AST];
  __shared__ float outB[K_ * AST];
  __shared__ float wbuf[CIN0 * 64];
  const int bs = blockIdx.x, t = threadIdx.x;
  build_x0(actA, xyz, points, knn_idx, newxyz, bs, t);
  loadw(wbuf, w0, CIN0 * 64, t);
  __syncthreads();
  matmul64<CIN0>(actA, wbuf, b0, outB, t);
  __syncthreads();
  stats64(outB, psum, psq, bs, 0, t);
}

// ---------------- Pass B ----------------
__global__ __launch_bounds__(256) void passB_kernel(
    const float* __restrict__ xyz, const float* __restrict__ points,
    const float* __restrict__ newxyz, const int* __restrict__ knn_idx,
    const float* __restrict__ w0, const float* __restrict__ b0,
    const float* __restrict__ w1, const float* __restrict__ b1,
    const float* __restrict__ scales, const float* __restrict__ shifts,
    float* __restrict__ psum, float* __restrict__ psq) {
  __shared__ float actA[K_ * AST];
  __shared__ float outB[K_ * AST];
  __shared__ float wbuf[CIN0 * 64];
  const int bs = blockIdx.x, t = threadIdx.x;
  build_x0(actA, xyz, points, knn_idx, newxyz, bs, t);
  loadw(wbuf, w0, CIN0 * 64, t);
  __syncthreads();
  matmul64<CIN0>(actA, wbuf, b0, outB, t);
  __syncthreads();
  norm_relu64(outB, scales, shifts, t);
  loadw(wbuf, w1, 64 * 64, t);
  __syncthreads();
  matmul64<64>(outB, wbuf, b1, actA, t);
  __syncthreads();
  stats64(actA, psum, psq, bs, 0, t);
}

// ---------------- Pass C ----------------
__global__ __launch_bounds__(256) void passC_kernel(
    const float* __restrict__ xyz, const float* __restrict__ points,
    const float* __restrict__ newxyz, const int* __restrict__ knn_idx,
    const float* __restrict__ w0, const float* __restrict__ b0,
    const float* __restrict__ w1, const float* __restrict__ b1,
    const float* __restrict__ w2, const float* __restrict__ b2,
    const float* __restrict__ scales, const float* __restrict__ shifts,
    float* __restrict__ psum, float* __restrict__ psq,
    float* __restrict__ maxraw, float* __restrict__ minbuf) {
  __shared__ float actA[K_ * AST];
  __shared__ float outB[K_ * AST];
  __shared__ float wbuf[CIN0 * 64];
  const int bs = blockIdx.x, t = threadIdx.x;
  build_x0(actA, xyz, points, knn_idx, newxyz, bs, t);
  loadw(wbuf, w0, CIN0 * 64, t);
  __syncthreads();
  matmul64<CIN0>(actA, wbuf, b0, outB, t);
  __syncthreads();
  norm_relu64(outB, scales, shifts, t);
  loadw(wbuf, w1, 64 * 64, t);
  __syncthreads();
  matmul64<64>(outB, wbuf, b1, actA, t);
  __syncthreads();
  norm_relu64(actA, scales + 128, shifts + 128, t);
  loadw_half(wbuf, w2, 0, t);
  __syncthreads();
  matmul64<64>(actA, wbuf, b2, outB, t);
  __syncthreads();
  stats64(outB, psum, psq, bs, 0, t);
  minmax64(outB, maxraw, minbuf, bs, 0, t);
  loadw_half(wbuf, w2, 64, t);
  __syncthreads();
  matmul64<64>(actA, wbuf, b2 + 64, outB, t);
  __syncthreads();
  stats64(outB, psum, psq, bs, 64, t);
  minmax64(outB, maxraw, minbuf, bs, 64, t);
}

// ---------------- BN finalize ----------------
__global__ __launch_bounds__(256) void finalize_kernel(
    const float* __restrict__ psum, const float* __restrict__ psq,
    const float* __restrict__ g, const float* __restrict__ be,
    float* __restrict__ scale, float* __restrict__ shift) {
  const int ch = blockIdx.x, t = threadIdx.x;
  __shared__ float ss[256];
  __shared__ float sq[256];
  float s = 0.f, q = 0.f;
  for (int p = t; p < NBS; p += 256) {
    s += psum[(size_t)p * 128 + ch];
    q += psq[(size_t)p * 128 + ch];
  }
  ss[t] = s; sq[t] = q;
  __syncthreads();
  for (int off = 128; off >= 1; off >>= 1) {
    if (t < off) { ss[t] += ss[t + off]; sq[t] += sq[t + off]; }
    __syncthreads();
  }
  if (t == 0) {
    const float invN = 1.0f / (float)(B_ * S_ * K_);
    const float mean = ss[0] * invN;
    const float var = sq[0] * invN - mean * mean;
    const float sc = g[ch] / sqrtf(var + 1e-5f);
    scale[ch] = sc;
    shift[ch] = be[ch] - mean * sc;
  }
}

// ---------------- Final ----------------
__global__ __launch_bounds__(256) void final_kernel(
    const float* __restrict__ minbuf, const float* __restrict__ scale,
    const float* __restrict__ shift, float* __restrict__ out) {
  const int i = blockIdx.x * 256 + threadIdx.x;  // < B*S*128
  const int ch = i & 127;
  const float sc = scale[ch], sh = shift[ch];
  const float mx = out[NEWXYZ_FLOATS + i];
  const float mn = minbuf[i];
  const float v = sc * (sc >= 0.f ? mx : mn) + sh;
  out[NEWXYZ_FLOATS + i] = fmaxf(v, 0.f);
}

// ---------------- host ----------------
extern "C" void kernel_launch(void* const* d_in, const int* in_sizes, int n_in,
                              void* d_out, int out_size, void* d_ws, size_t ws_size,
                              hipStream_t stream) {
  const float* xyz = (const float*)d_in[0];
  const float* points = (const float*)d_in[1];
  const float* w0 = (const float*)d_in[2];
  const float* b0 = (const float*)d_in[3];
  const float* g0 = (const float*)d_in[4];
  const float* be0 = (const float*)d_in[5];
  const float* w1 = (const float*)d_in[6];
  const float* b1 = (const float*)d_in[7];
  const float* g1 = (const float*)d_in[8];
  const float* be1 = (const float*)d_in[9];
  const float* w2 = (const float*)d_in[10];
  const float* b2 = (const float*)d_in[11];
  const float* g2 = (const float*)d_in[12];
  const float* be2 = (const float*)d_in[13];
  float* out = (float*)d_out;

  float* ws = (float*)d_ws;
  int* knn_idx = (int*)ws;                 // B*S*K ints
  float* psum = ws + 524288;
  float* psq = psum + (size_t)NBS * 128;
  float* scales = psq + (size_t)NBS * 128;
  float* shifts = scales + 384;
  float* minbuf = shifts + 384;
  float* newxyz = out;
  float* maxraw = out + NEWXYZ_FLOATS;

  fps_kernel<<<B_, 256, 0, stream>>>(xyz, newxyz);
  knn_kernel<<<NBS / 4, 256, 0, stream>>>(xyz, newxyz, knn_idx);
  passA_kernel<<<NBS, 256, 0, stream>>>(xyz, points, newxyz, knn_idx, w0, b0, psum, psq);
  finalize_kernel<<<64, 256, 0, stream>>>(psum, psq, g0, be0, scales, shifts);
  passB_kernel<<<NBS, 256, 0, stream>>>(xyz, points, newxyz, knn_idx, w0, b0, w1, b1,
                                        scales, shifts, psum, psq);
  finalize_kernel<<<64, 256, 0, stream>>>(psum, psq, g1, be1, scales + 128, shifts + 128);
  passC_kernel<<<NBS, 256, 0, stream>>>(xyz, points, newxyz, knn_idx, w0, b0, w1, b1, w2, b2,
                                        scales, shifts, psum, psq, maxraw, minbuf);
  finalize_kernel<<<128, 256, 0, stream>>>(psum, psq, g2, be2, scales + 256, shifts + 256);
  final_kernel<<<(B_ * S_ * 128) / 256, 256, 0, stream>>>(minbuf, scales + 256, shifts + 256, out);
}